// Round 9
// baseline (273.605 us; speedup 1.0000x reference)
//
#include <hip/hip_runtime.h>
#include <type_traits>

namespace {
constexpr int HH = 512;
constexpr int WW = 512;
constexpr int KS = 11;
constexpr int PADR = 5;
constexpr int TH = 32;                 // tile rows per block
constexpr int TW = 64;                 // tile cols per block
constexpr int SLAB = 8;                // rows per slab (4 slabs per block)
constexpr int NCP = 38;                // col-pairs: 76 local cols (halo 6+6)
constexpr int PAF = 180;               // interleaved plane pitch (floats):
                                       // 180%32==20 -> R6's measured-free
                                       // b128 bank residue; %4==0 -> 16B rows
constexpr int PCF = 84;                // scalar plane pitch: 84%32==20, %4==0
constexpr int NTHREADS = 128;          // 2 waves per block
constexpr float SSIM_C1 = 1.0e-4f;     // (0.01*1.0)^2
constexpr float SSIM_C2 = 9.0e-4f;     // (0.03*1.0)^2
}

typedef float v2f __attribute__((ext_vector_type(2)));
typedef float v4f __attribute__((ext_vector_type(4)));
#define LOWP(v)  __builtin_shufflevector(v, v, 0, 1)
#define HIGHP(v) __builtin_shufflevector(v, v, 2, 3)

// R6 structure (verified best: 107us, block-slab barriers, FETCH 118MB; R7
// proved wave-free-running doubles FETCH and loses) + two levers:
//  - phase-1 COLUMN pairing: each position = 2 cols x 2 rows via v2f global
//    loads (left halo widened to 6 so loads are 8B-aligned). VMEM
//    instructions/output halve, address VALU halves, products packed across
//    columns. State = 10 named v2f = 20 floats, the R5/R6-proven spelling.
//  - 128-thread blocks, SLAB=8, 4 slabs: LDS 14.2KB -> 11 blocks/CU
//    (22 waves), barrier groups of 2 waves instead of 4 -> latency bubbles
//    filled by independent blocks, locality shape unchanged.
// Phase-2 keeps the R6-proven packed conv; window shifts one column so
// reads are 8 b128 with HIGH/LOW pair re-indexing (still 16B-aligned).
// [R8 bench was an infra failure ("container failed twice"), not a kernel
//  verdict; source re-audited for OOB/hang -- memory-safe. Resubmitted
//  unchanged.]
__global__ __launch_bounds__(NTHREADS, 6) void ssim_fused(
    const float* __restrict__ x, const float* __restrict__ y,
    const float* __restrict__ kern, float* __restrict__ out)
{
    __shared__ __align__(16) float pA[SLAB * PAF];   // (sx,sy) interleaved
    __shared__ __align__(16) float pB_[SLAB * PAF];  // (sxx,syy) interleaved
    __shared__ __align__(16) float pC_[SLAB * PCF];  // sxy scalar
    // 2*5760 + 2688 = 14208 B -> 11 blocks/CU (156.3 of 160 KB LDS)

    constexpr int tiles_w = WW / TW;         // 8
    constexpr int tiles_h = HH / TH;         // 16
    constexpr int tpp = tiles_w * tiles_h;   // 128 tiles per plane

    const int bid = blockIdx.x;
    const int plane = bid / tpp;
    const int trem = bid - plane * tpp;
    const int tr_idx = trem / tiles_w;
    const int tile_r = tr_idx * TH;
    const int tile_c = (trem - tr_idx * tiles_w) * TW;

    const float* __restrict__ xp = x + (size_t)plane * (HH * WW);
    const float* __restrict__ yp = y + (size_t)plane * (HH * WW);
    float* __restrict__ op = out + (size_t)plane * (HH * WW);

    // 1D gaussian weights (exact for outer products), broadcast pairs.
    v2f pw[6];
    {
        const float inv = rsqrtf(kern[5 * KS + 5]);
#pragma unroll
        for (int i = 0; i < 6; ++i) {
            const float w = kern[5 * KS + i] * inv;
            v2f tmp = {w, w};
            pw[i] = tmp;
        }
    }

    const int t = threadIdx.x;
    // interior now needs 6 cols of left halo (aligned v2f) and 70 on right
    const bool interior = (tile_r >= PADR) && (tile_r + TH + PADR <= HH) &&
                          (tile_c >= 6) && (tile_c + 70 <= WW);

    // phase-2 mapping: 8 rows x 16 col-groups of 4 outputs
    const int p2_r = t >> 4;           // 0..7
    const int p2_m = t & 15;           // outputs tile_c + 4*p2_m .. +3

    auto run_slab = [&](int s0, auto intr_tag) {
        constexpr bool INTR = decltype(intr_tag)::value;
        // ---- phase 1: vertical 11-tap blur, 2col x 2row patches, packed.
        // 4 row-pairs x 38 col-pairs = 152 positions over 128 threads.
        for (int i = t; i < 4 * NCP; i += NTHREADS) {
            const int r2 = i / NCP;
            const int cp = i - r2 * NCP;
            const int gr = tile_r + s0 + 2 * r2;   // first output row of pair
            const int gc = tile_c - 6 + 2 * cp;    // even -> aligned v2f
            v2f sxA = {0.f, 0.f}, syA = {0.f, 0.f}, sxxA = {0.f, 0.f},
                syyA = {0.f, 0.f}, sxyA = {0.f, 0.f};
            v2f sxB = {0.f, 0.f}, syB = {0.f, 0.f}, sxxB = {0.f, 0.f},
                syyB = {0.f, 0.f}, sxyB = {0.f, 0.f};
            const float* xq = xp + (gr - PADR) * WW + gc;
            const float* yq = yp + (gr - PADR) * WW + gc;
#pragma unroll
            for (int k = 0; k < KS + 1; ++k) {       // 12 input rows
                v2f xv, yv;
                if (INTR) {
                    xv = *(const v2f*)(xq + k * WW);
                    yv = *(const v2f*)(yq + k * WW);
                } else {
                    const int rr = gr - PADR + k;
                    const bool okr = (rr >= 0) & (rr < HH);
                    float x0 = 0.f, x1 = 0.f, y0 = 0.f, y1 = 0.f;
                    if (okr & (gc >= 0) & (gc < WW)) {
                        x0 = xp[rr * WW + gc];
                        y0 = yp[rr * WW + gc];
                    }
                    if (okr & (gc + 1 >= 0) & (gc + 1 < WW)) {
                        x1 = xp[rr * WW + gc + 1];
                        y1 = yp[rr * WW + gc + 1];
                    }
                    v2f tx = {x0, x1}; xv = tx;
                    v2f ty = {y0, y1}; yv = ty;
                }
                const v2f xx = xv * xv;              // v_pk_mul_f32
                const v2f yy = yv * yv;
                const v2f xy = xv * yv;
                if (k < KS) {                        // row A taps 0..10
                    const v2f w = pw[k < 6 ? k : 10 - k];
                    sxA += w * xv;  syA += w * yv;   // v_pk_fma_f32
                    sxxA += w * xx; syyA += w * yy; sxyA += w * xy;
                }
                if (k >= 1) {                        // row B taps 0..10
                    const v2f w = pw[(k - 1) < 6 ? (k - 1) : 11 - k];
                    sxB += w * xv;  syB += w * yv;
                    sxxB += w * xx; syyB += w * yy; sxyB += w * xy;
                }
            }
            const int rA = 2 * r2, rB = 2 * r2 + 1;
            v4f uA = {sxA.x, syA.x, sxA.y, syA.y};
            v4f qA = {sxxA.x, syyA.x, sxxA.y, syyA.y};
            v4f uB = {sxB.x, syB.x, sxB.y, syB.y};
            v4f qB = {sxxB.x, syyB.x, sxxB.y, syyB.y};
            *(v4f*)&pA[rA * PAF + 4 * cp] = uA;
            *(v4f*)&pA[rB * PAF + 4 * cp] = uB;
            *(v4f*)&pB_[rA * PAF + 4 * cp] = qA;
            *(v4f*)&pB_[rB * PAF + 4 * cp] = qB;
            *(v2f*)&pC_[rA * PCF + 2 * cp] = sxyA;
            *(v2f*)&pC_[rB * PCF + 2 * cp] = sxyB;
        }
        __syncthreads();

        // ---- phase 2: horizontal 11-tap blur (packed) + SSIM.
        // Local col of output j=0 is lc = 4*p2_m + 6; window lc-5..lc+8 ->
        // float offsets [8*p2_m+2, 8*p2_m+30): 8 aligned b128 reads, pairs
        // re-indexed HIGH/LOW (window starts mid-v4f).
#define PCONV(R0, R1, R2, R3, P0, P1, P2, P3, P4, P5, P6, P7, P8, P9, P10, P11, P12, P13) \
    R0 += pw[0]*P0; R0 += pw[1]*P1; R0 += pw[2]*P2; R0 += pw[3]*P3;             \
    R0 += pw[4]*P4; R0 += pw[5]*P5; R0 += pw[4]*P6; R0 += pw[3]*P7;             \
    R0 += pw[2]*P8; R0 += pw[1]*P9; R0 += pw[0]*P10;                            \
    R1 += pw[0]*P1; R1 += pw[1]*P2; R1 += pw[2]*P3; R1 += pw[3]*P4;             \
    R1 += pw[4]*P5; R1 += pw[5]*P6; R1 += pw[4]*P7; R1 += pw[3]*P8;             \
    R1 += pw[2]*P9; R1 += pw[1]*P10; R1 += pw[0]*P11;                           \
    R2 += pw[0]*P2; R2 += pw[1]*P3; R2 += pw[2]*P4; R2 += pw[3]*P5;             \
    R2 += pw[4]*P6; R2 += pw[5]*P7; R2 += pw[4]*P8; R2 += pw[3]*P9;             \
    R2 += pw[2]*P10; R2 += pw[1]*P11; R2 += pw[0]*P12;                          \
    R3 += pw[0]*P3; R3 += pw[1]*P4; R3 += pw[2]*P5; R3 += pw[3]*P6;             \
    R3 += pw[4]*P7; R3 += pw[5]*P8; R3 += pw[4]*P9; R3 += pw[3]*P10;            \
    R3 += pw[2]*P11; R3 += pw[1]*P12; R3 += pw[0]*P13;

#define SCONV(R, S0, S1, S2, S3, S4, S5, S6, S7, S8, S9, S10)                   \
    R += pw[0].x*S0; R += pw[1].x*S1; R += pw[2].x*S2; R += pw[3].x*S3;         \
    R += pw[4].x*S4; R += pw[5].x*S5; R += pw[4].x*S6; R += pw[3].x*S7;         \
    R += pw[2].x*S8; R += pw[1].x*S9; R += pw[0].x*S10;

        v2f rUV0 = {0.f, 0.f}, rUV1 = {0.f, 0.f}, rUV2 = {0.f, 0.f}, rUV3 = {0.f, 0.f};
        {
            const float* rowA = &pA[p2_r * PAF + 8 * p2_m];
            const v4f b0 = *(const v4f*)(rowA + 0);
            const v4f b1 = *(const v4f*)(rowA + 4);
            const v4f b2 = *(const v4f*)(rowA + 8);
            const v4f b3 = *(const v4f*)(rowA + 12);
            const v4f b4 = *(const v4f*)(rowA + 16);
            const v4f b5 = *(const v4f*)(rowA + 20);
            const v4f b6 = *(const v4f*)(rowA + 24);
            const v4f b7 = *(const v4f*)(rowA + 28);
            PCONV(rUV0, rUV1, rUV2, rUV3,
                  HIGHP(b0), LOWP(b1), HIGHP(b1), LOWP(b2), HIGHP(b2),
                  LOWP(b3), HIGHP(b3), LOWP(b4), HIGHP(b4), LOWP(b5),
                  HIGHP(b5), LOWP(b6), HIGHP(b6), LOWP(b7))
        }
        v2f rQQ0 = {0.f, 0.f}, rQQ1 = {0.f, 0.f}, rQQ2 = {0.f, 0.f}, rQQ3 = {0.f, 0.f};
        {
            const float* rowB = &pB_[p2_r * PAF + 8 * p2_m];
            const v4f b0 = *(const v4f*)(rowB + 0);
            const v4f b1 = *(const v4f*)(rowB + 4);
            const v4f b2 = *(const v4f*)(rowB + 8);
            const v4f b3 = *(const v4f*)(rowB + 12);
            const v4f b4 = *(const v4f*)(rowB + 16);
            const v4f b5 = *(const v4f*)(rowB + 20);
            const v4f b6 = *(const v4f*)(rowB + 24);
            const v4f b7 = *(const v4f*)(rowB + 28);
            PCONV(rQQ0, rQQ1, rQQ2, rQQ3,
                  HIGHP(b0), LOWP(b1), HIGHP(b1), LOWP(b2), HIGHP(b2),
                  LOWP(b3), HIGHP(b3), LOWP(b4), HIGHP(b4), LOWP(b5),
                  HIGHP(b5), LOWP(b6), HIGHP(b6), LOWP(b7))
        }
        float rC0 = 0.f, rC1 = 0.f, rC2 = 0.f, rC3 = 0.f;
        {
            const float* rowC = &pC_[p2_r * PCF + 4 * p2_m];
            const v4f c0 = *(const v4f*)(rowC + 0);
            const v4f c1 = *(const v4f*)(rowC + 4);
            const v4f c2 = *(const v4f*)(rowC + 8);
            const v4f c3 = *(const v4f*)(rowC + 12);
            const float f1 = c0.y, f2 = c0.z, f3 = c0.w;
            const float f4 = c1.x, f5 = c1.y, f6 = c1.z, f7 = c1.w;
            const float f8 = c2.x, f9 = c2.y, f10 = c2.z, f11 = c2.w;
            const float f12 = c3.x, f13 = c3.y, f14 = c3.z;
            SCONV(rC0, f1, f2, f3, f4, f5, f6, f7, f8, f9, f10, f11)
            SCONV(rC1, f2, f3, f4, f5, f6, f7, f8, f9, f10, f11, f12)
            SCONV(rC2, f3, f4, f5, f6, f7, f8, f9, f10, f11, f12, f13)
            SCONV(rC3, f4, f5, f6, f7, f8, f9, f10, f11, f12, f13, f14)
        }

        float4 o4;
#pragma unroll
        for (int j = 0; j < 4; ++j) {
            const v2f uvj = (j == 0) ? rUV0 : (j == 1) ? rUV1 : (j == 2) ? rUV2 : rUV3;
            const v2f qqj = (j == 0) ? rQQ0 : (j == 1) ? rQQ1 : (j == 2) ? rQQ2 : rQQ3;
            const float uxy = (j == 0) ? rC0 : (j == 1) ? rC1 : (j == 2) ? rC2 : rC3;
            const float ux = uvj.x, uy = uvj.y;
            const float uxx = qqj.x, uyy = qqj.y;
            const float vx  = uxx - ux * ux;
            const float vy  = uyy - uy * uy;
            const float vxy = uxy - ux * uy;
            const float a1s = 2.f * ux * uy + SSIM_C1;
            const float a2s = 2.f * vxy + SSIM_C2;
            const float b1s = ux * ux + uy * uy + SSIM_C1;
            const float b2s = vx + vy + SSIM_C2;
            (&o4.x)[j] = (a1s * a2s) * __builtin_amdgcn_rcpf(b1s * b2s);
        }
        *(float4*)(op + (size_t)(tile_r + s0 + p2_r) * WW + (tile_c + 4 * p2_m)) = o4;
        __syncthreads();   // LDS reused by next slab
#undef PCONV
#undef SCONV
    };

    if (interior) {
        run_slab(0,         std::true_type{});
        run_slab(SLAB,      std::true_type{});
        run_slab(2 * SLAB,  std::true_type{});
        run_slab(3 * SLAB,  std::true_type{});
    } else {
        run_slab(0,         std::false_type{});
        run_slab(SLAB,      std::false_type{});
        run_slab(2 * SLAB,  std::false_type{});
        run_slab(3 * SLAB,  std::false_type{});
    }
}

extern "C" void kernel_launch(void* const* d_in, const int* in_sizes, int n_in,
                              void* d_out, int out_size, void* d_ws, size_t ws_size,
                              hipStream_t stream) {
    const float* x    = (const float*)d_in[0];
    const float* y    = (const float*)d_in[1];
    const float* kern = (const float*)d_in[2];
    float* out = (float*)d_out;

    const int nplanes = in_sizes[0] / (HH * WW);            // 48
    const int nblocks = nplanes * (HH / TH) * (WW / TW);    // 6144

    ssim_fused<<<dim3(nblocks), dim3(NTHREADS), 0, stream>>>(x, y, kern, out);
}

// Round 10
// 196.576 us; speedup vs baseline: 1.3919x; 1.3919x over previous
//
#include <hip/hip_runtime.h>
#include <type_traits>

namespace {
constexpr int HH = 512;
constexpr int WW = 512;
constexpr int KS = 11;
constexpr int PADR = 5;
constexpr int TH = 32;                 // tile rows per block
constexpr int TW = 64;                 // tile cols per block
constexpr int SLAB = 16;               // rows per slab
constexpr int HC = TW + 2 * PADR;      // 74 columns incl. horizontal halo
constexpr int LPA = 148;               // interleaved pair rows: 74 cols x 2
constexpr int LPC = 76;                // scalar sxy rows
constexpr int NTHREADS = 512;          // 8 waves per block
constexpr float SSIM_C1 = 1.0e-4f;     // (0.01*1.0)^2
constexpr float SSIM_C2 = 9.0e-4f;     // (0.03*1.0)^2
}

typedef float v2f __attribute__((ext_vector_type(2)));
typedef float v4f __attribute__((ext_vector_type(4)));
#define LOWP(v)  __builtin_shufflevector(v, v, 0, 1)
#define HIGHP(v) __builtin_shufflevector(v, v, 2, 3)

// R6 kernel (verified best: 107us, VALU 53%, occ 55%, FETCH 118MB) with ONE
// change: 512-thread blocks (8 waves) on the SAME 32x64 tile / 16-row slab /
// LDS layout. R9's regression (SLAB=8 + 128-thr: FETCH 245MB, WRITE 93MB)
// reconfirmed the R6 locality shape must not change; R7 proved barriers
// aren't the bubble -- the residual is phase-correlated load-burst latency
// with only 24 resident waves. 8 waves x 4 blocks/CU = 32 waves (HW max,
// LDS 4x23.8=95KB), phase-1 critical path 3->2 positions/thread
// (592/512=1.16). Phase 2 keeps R6's exact verified mapping: threads >=256
// idle there (SIMD issue is shared across all resident waves, so per-CU
// phase-2 throughput is unchanged). launch_bounds(512,8) caps VGPR at 64
// (measured need: 40).
__global__ __launch_bounds__(NTHREADS, 8) void ssim_fused(
    const float* __restrict__ x, const float* __restrict__ y,
    const float* __restrict__ kern, float* __restrict__ out)
{
    __shared__ __align__(16) float pA[SLAB][LPA];   // (sx,sy) interleaved
    __shared__ __align__(16) float pB_[SLAB][LPA];  // (sxx,syy) interleaved
    __shared__ __align__(16) float pC_[SLAB][LPC];  // sxy scalar
    // total 23808 B; 4 blocks/CU (wave-capped) = 95KB of 160KB LDS

    constexpr int tiles_w = WW / TW;         // 8
    constexpr int tiles_h = HH / TH;         // 16
    constexpr int tpp = tiles_w * tiles_h;   // 128 tiles per plane

    const int bid = blockIdx.x;
    const int plane = bid / tpp;
    const int trem = bid - plane * tpp;
    const int tr_idx = trem / tiles_w;
    const int tile_r = tr_idx * TH;
    const int tile_c = (trem - tr_idx * tiles_w) * TW;

    const float* __restrict__ xp = x + (size_t)plane * (HH * WW);
    const float* __restrict__ yp = y + (size_t)plane * (HH * WW);
    float* __restrict__ op = out + (size_t)plane * (HH * WW);

    // 1D gaussian weights (exact for outer products), broadcast pairs.
    // Kernel is symmetric: taps 6..10 mirror 4..0 -> 6 unique weights.
    v2f pw[6];
    {
        const float inv = rsqrtf(kern[5 * KS + 5]);
#pragma unroll
        for (int i = 0; i < 6; ++i) {
            const float w = kern[5 * KS + i] * inv;
            v2f tmp = {w, w};
            pw[i] = tmp;
        }
    }

    const int t = threadIdx.x;
    const bool interior = (tile_r >= PADR) && (tile_r + TH + PADR <= HH) &&
                          (tile_c >= PADR) && (tile_c + TW + PADR <= WW);

    // phase-2 mapping (threads 0..255 only): one 4-wide group per thread
    const int p2_r = t >> 4;           // 0..15 (for t < 256)
    const int p2_m = t & 15;           // col group; outputs 4*p2_m .. +3

    auto run_slab = [&](int s0, auto intr_tag) {
        constexpr bool INTR = decltype(intr_tag)::value;
        // ---- phase 1: vertical 11-tap blur into LDS, row pairs, packed.
        // 8 row-pairs x 74 cols = 592 positions over 512 threads (1.16).
        for (int i = t; i < (SLAB / 2) * HC; i += NTHREADS) {
            const int r2 = i / HC;
            const int c = i - r2 * HC;
            const int gr = tile_r + s0 + 2 * r2;   // first output row of pair
            const int gc = tile_c + c - PADR;      // input col (maybe OOB)
            v2f uvA = {0.f, 0.f}, qqA = {0.f, 0.f};
            v2f uvB = {0.f, 0.f}, qqB = {0.f, 0.f};
            float xyA = 0.f, xyB = 0.f;
            const float* xq = xp + (gr - PADR) * WW + gc;
            const float* yq = yp + (gr - PADR) * WW + gc;
#pragma unroll
            for (int k = 0; k < KS + 1; ++k) {       // 12 input rows
                float xv, yv;
                if (INTR) {
                    xv = xq[k * WW];
                    yv = yq[k * WW];
                } else {
                    const int rr = gr - PADR + k;
                    const bool ok = (gc >= 0) & (gc < WW) & (rr >= 0) & (rr < HH);
                    xv = 0.f; yv = 0.f;
                    if (ok) {
                        xv = xp[rr * WW + gc];
                        yv = yp[rr * WW + gc];
                    }
                }
                v2f v2 = {xv, yv};
                const v2f q2 = v2 * v2;              // v_pk_mul_f32
                const float xy = xv * yv;
                if (k < KS) {                        // row A taps 0..10
                    const v2f w = pw[k < 6 ? k : 10 - k];
                    uvA += w * v2;                   // v_pk_fma_f32
                    qqA += w * q2;
                    xyA += w.x * xy;
                }
                if (k >= 1) {                        // row B taps 0..10
                    const v2f w = pw[(k - 1) < 6 ? (k - 1) : 11 - k];
                    uvB += w * v2;
                    qqB += w * q2;
                    xyB += w.x * xy;
                }
            }
            const int rA = 2 * r2, rB = 2 * r2 + 1;
            *(v2f*)&pA[rA][2 * c] = uvA;   *(v2f*)&pA[rB][2 * c] = uvB;
            *(v2f*)&pB_[rA][2 * c] = qqA;  *(v2f*)&pB_[rB][2 * c] = qqB;
            pC_[rA][c] = xyA;              pC_[rB][c] = xyB;
        }
        __syncthreads();

        // ---- phase 2: horizontal 11-tap blur (packed) + SSIM.
        // Threads 0..255 only; mapping identical to the verified R6 kernel.
#define PCONV(R0, R1, R2, R3, a0, a1, a2, a3, a4, a5, a6)                       \
    R0 += pw[0]*LOWP(a0); R0 += pw[1]*HIGHP(a0); R0 += pw[2]*LOWP(a1);          \
    R0 += pw[3]*HIGHP(a1); R0 += pw[4]*LOWP(a2); R0 += pw[5]*HIGHP(a2);         \
    R0 += pw[4]*LOWP(a3); R0 += pw[3]*HIGHP(a3); R0 += pw[2]*LOWP(a4);          \
    R0 += pw[1]*HIGHP(a4); R0 += pw[0]*LOWP(a5);                                \
    R1 += pw[0]*HIGHP(a0); R1 += pw[1]*LOWP(a1); R1 += pw[2]*HIGHP(a1);         \
    R1 += pw[3]*LOWP(a2); R1 += pw[4]*HIGHP(a2); R1 += pw[5]*LOWP(a3);          \
    R1 += pw[4]*HIGHP(a3); R1 += pw[3]*LOWP(a4); R1 += pw[2]*HIGHP(a4);         \
    R1 += pw[1]*LOWP(a5); R1 += pw[0]*HIGHP(a5);                                \
    R2 += pw[0]*LOWP(a1); R2 += pw[1]*HIGHP(a1); R2 += pw[2]*LOWP(a2);          \
    R2 += pw[3]*HIGHP(a2); R2 += pw[4]*LOWP(a3); R2 += pw[5]*HIGHP(a3);         \
    R2 += pw[4]*LOWP(a4); R2 += pw[3]*HIGHP(a4); R2 += pw[2]*LOWP(a5);          \
    R2 += pw[1]*HIGHP(a5); R2 += pw[0]*LOWP(a6);                                \
    R3 += pw[0]*HIGHP(a1); R3 += pw[1]*LOWP(a2); R3 += pw[2]*HIGHP(a2);         \
    R3 += pw[3]*LOWP(a3); R3 += pw[4]*HIGHP(a3); R3 += pw[5]*LOWP(a4);          \
    R3 += pw[4]*HIGHP(a4); R3 += pw[3]*LOWP(a5); R3 += pw[2]*HIGHP(a5);         \
    R3 += pw[1]*LOWP(a6); R3 += pw[0]*HIGHP(a6);

#define SCONV(R, S0, S1, S2, S3, S4, S5, S6, S7, S8, S9, S10)                   \
    R += pw[0].x*S0; R += pw[1].x*S1; R += pw[2].x*S2; R += pw[3].x*S3;         \
    R += pw[4].x*S4; R += pw[5].x*S5; R += pw[4].x*S6; R += pw[3].x*S7;         \
    R += pw[2].x*S8; R += pw[1].x*S9; R += pw[0].x*S10;

        if (t < 256) {
            v2f rUV0 = {0.f, 0.f}, rUV1 = {0.f, 0.f}, rUV2 = {0.f, 0.f}, rUV3 = {0.f, 0.f};
            {
                const float* rowA = &pA[p2_r][8 * p2_m];
                const v4f a0 = *(const v4f*)(rowA + 0);
                const v4f a1 = *(const v4f*)(rowA + 4);
                const v4f a2 = *(const v4f*)(rowA + 8);
                const v4f a3 = *(const v4f*)(rowA + 12);
                const v4f a4 = *(const v4f*)(rowA + 16);
                const v4f a5 = *(const v4f*)(rowA + 20);
                const v4f a6 = *(const v4f*)(rowA + 24);
                PCONV(rUV0, rUV1, rUV2, rUV3, a0, a1, a2, a3, a4, a5, a6)
            }
            v2f rQQ0 = {0.f, 0.f}, rQQ1 = {0.f, 0.f}, rQQ2 = {0.f, 0.f}, rQQ3 = {0.f, 0.f};
            {
                const float* rowB = &pB_[p2_r][8 * p2_m];
                const v4f a0 = *(const v4f*)(rowB + 0);
                const v4f a1 = *(const v4f*)(rowB + 4);
                const v4f a2 = *(const v4f*)(rowB + 8);
                const v4f a3 = *(const v4f*)(rowB + 12);
                const v4f a4 = *(const v4f*)(rowB + 16);
                const v4f a5 = *(const v4f*)(rowB + 20);
                const v4f a6 = *(const v4f*)(rowB + 24);
                PCONV(rQQ0, rQQ1, rQQ2, rQQ3, a0, a1, a2, a3, a4, a5, a6)
            }
            float rC0 = 0.f, rC1 = 0.f, rC2 = 0.f, rC3 = 0.f;
            {
                const float* rowC = &pC_[p2_r][4 * p2_m];
                const v4f c0 = *(const v4f*)(rowC + 0);
                const v4f c1 = *(const v4f*)(rowC + 4);
                const v4f c2 = *(const v4f*)(rowC + 8);
                const v4f c3 = *(const v4f*)(rowC + 12);
                const float e0 = c0.x, e1 = c0.y, e2 = c0.z, e3 = c0.w;
                const float e4 = c1.x, e5 = c1.y, e6 = c1.z, e7 = c1.w;
                const float e8 = c2.x, e9 = c2.y, e10 = c2.z, e11 = c2.w;
                const float e12 = c3.x, e13 = c3.y;
                SCONV(rC0, e0, e1, e2, e3, e4, e5, e6, e7, e8, e9, e10)
                SCONV(rC1, e1, e2, e3, e4, e5, e6, e7, e8, e9, e10, e11)
                SCONV(rC2, e2, e3, e4, e5, e6, e7, e8, e9, e10, e11, e12)
                SCONV(rC3, e3, e4, e5, e6, e7, e8, e9, e10, e11, e12, e13)
            }

            float4 o4;
#pragma unroll
            for (int j = 0; j < 4; ++j) {
                const v2f uvj = (j == 0) ? rUV0 : (j == 1) ? rUV1 : (j == 2) ? rUV2 : rUV3;
                const v2f qqj = (j == 0) ? rQQ0 : (j == 1) ? rQQ1 : (j == 2) ? rQQ2 : rQQ3;
                const float uxy = (j == 0) ? rC0 : (j == 1) ? rC1 : (j == 2) ? rC2 : rC3;
                const float ux = uvj.x, uy = uvj.y;
                const float uxx = qqj.x, uyy = qqj.y;
                const float vx  = uxx - ux * ux;
                const float vy  = uyy - uy * uy;
                const float vxy = uxy - ux * uy;
                const float a1s = 2.f * ux * uy + SSIM_C1;
                const float a2s = 2.f * vxy + SSIM_C2;
                const float b1s = ux * ux + uy * uy + SSIM_C1;
                const float b2s = vx + vy + SSIM_C2;
                (&o4.x)[j] = (a1s * a2s) * __builtin_amdgcn_rcpf(b1s * b2s);
            }
            *(float4*)(op + (size_t)(tile_r + s0 + p2_r) * WW + (tile_c + 4 * p2_m)) = o4;
        }
        __syncthreads();   // LDS reused by next slab
#undef PCONV
#undef SCONV
    };

    if (interior) {
        run_slab(0,    std::true_type{});
        run_slab(SLAB, std::true_type{});
    } else {
        run_slab(0,    std::false_type{});
        run_slab(SLAB, std::false_type{});
    }
}

extern "C" void kernel_launch(void* const* d_in, const int* in_sizes, int n_in,
                              void* d_out, int out_size, void* d_ws, size_t ws_size,
                              hipStream_t stream) {
    const float* x    = (const float*)d_in[0];
    const float* y    = (const float*)d_in[1];
    const float* kern = (const float*)d_in[2];
    float* out = (float*)d_out;

    const int nplanes = in_sizes[0] / (HH * WW);            // 48
    const int nblocks = nplanes * (HH / TH) * (WW / TW);    // 6144

    ssim_fused<<<dim3(nblocks), dim3(NTHREADS), 0, stream>>>(x, y, kern, out);
}